// Round 1
// baseline (10925.311 us; speedup 1.0000x reference)
//
#include <hip/hip_runtime.h>
#include <stdint.h>
#include <stddef.h>

#define S_LEN 512
#define BATCH 256
#define NIN   64
#define HD    512
#define G4    2048   // 4*H
#define RING_D 32    // ring depth (pow2); back-pressure slack = 30 steps

typedef _Float16 f16;
typedef _Float16 f16x8 __attribute__((ext_vector_type(8)));
typedef float    f32x4 __attribute__((ext_vector_type(4)));
typedef uint32_t u32x4 __attribute__((ext_vector_type(4)));

// ============================ prep kernels ============================
__global__ void k_f32_to_f16(const float* __restrict__ src, f16* __restrict__ dst, int n) {
  int i = blockIdx.x * 256 + threadIdx.x;
  if (i < n) dst[i] = (f16)src[i];
}

// x [B,S,I] fp32 -> xin [(s*256+b)*64+i] fp16  (seq-major rows)
__global__ void k_x_transpose(const float* __restrict__ x, f16* __restrict__ xin) {
  int idx = blockIdx.x * 256 + threadIdx.x;
  int i  = idx & 63;
  int sb = idx >> 6;
  int b  = sb & 255;
  int s  = sb >> 8;
  xin[idx] = (f16)x[((size_t)b * S_LEN + s) * NIN + i];
}

__global__ void k_zero_i32(uint32_t* p, int n) {
  int i = blockIdx.x * 256 + threadIdx.x;
  if (i < n) p[i] = 0u;
}

// ====================== fused 3-layer systolic LSTM ======================
// ONE launch, 768 WGs x 512 threads (3 WGs/CU -> all resident; required, see back-pressure).
// blockIdx = l*256 + gi*16 + bi.  WG (l,bi,gi): layer l, batch rows [bi*16,+16),
// hidden cols [gi*32,+32) across 4 gates.  Same-bi WGs (all layers, all gi) share
// blockIdx%8 -> same XCD.
//
// Per step t, WG of layer l:
//   needs own-layer flags >= t        (h_{l,t-1} in ring slot t%D)
//   needs prev-layer flags >= t+1     (h_{l-1,t} in slot (t+1)%D)  [l>0; l==0 reads static x]
//   needs next-layer flags >= t+2-D   (back-pressure before overwriting slot (t+1)%D)
// Wave 0 polls all three 64B flag lines (lane role = lane>>4); everyone else waits at the
// barrier -> poll traffic stays ~3 lines/WG/sweep (R6-proven regime, no R5 storm).
// Then: stage own h + prev h (coalesced relaxed u64 MALL loads) -> LDS; 16 MFMA recurrence
// + 16 MFMA input projection (2 for l==0) into ONE fp32 acc; gates+bias -> elementwise ->
// h store to ring slot (t+1)%D; barrier drains vmcnt; tid0 bumps flag.
__global__ __launch_bounds__(512, 6) void k_fused(
    const f16* __restrict__ whh,     // [3][2048][512] fp16
    const f16* __restrict__ wih,     // [3][2048][512] fp16 (layer0 uses [2048][64])
    const float* __restrict__ b0,
    const float* __restrict__ b1,
    const float* __restrict__ b2,
    const f16* __restrict__ xin,     // [512*256][64] fp16
    f16* __restrict__ ring,          // [3][RING_D][256][512] fp16
    int* __restrict__ flags,         // [3][256]
    f16* __restrict__ hlast) {       // [256][512] fp16 (layer-2 final h)
  const int tid  = threadIdx.x;
  const int lane = tid & 63;
  const int wave = tid >> 6;          // 0..7
  const int l    = blockIdx.x >> 8;   // 0..2
  const int idx  = blockIdx.x & 255;
  const int gi   = idx >> 4;
  const int bi   = idx & 15;
  const int ln   = lane & 15;
  const int quad = lane >> 4;

  __shared__ f16   lh [16 * 520];     // own-layer h_{t-1} tile, pitch 520 f16
  __shared__ f16   lhp[16 * 520];     // prev-layer h_t tile (or x tile for l==0)
  __shared__ float lgate[16 * 132];   // gate accum [16 b][128], pitch 132

  const f16* whh_l = whh + (size_t)l * G4 * HD;
  const f16* wih_l = wih + (size_t)l * G4 * HD;
  const float* bias_l = (l == 0) ? b0 : (l == 1 ? b1 : b2);

  // --- weight fragments -> registers (once); asm launder pins them ---
  const int grow = (wave >> 1) * HD + gi * 32 + (wave & 1) * 16 + ln; // row in [2048,K]
  f16x8 wfh[16];
#pragma unroll
  for (int ks = 0; ks < 16; ks++) {
    u32x4 t = *(const u32x4*)(whh_l + (size_t)grow * HD + ks * 32 + quad * 8);
    asm volatile("" : "+v"(t));
    wfh[ks] = __builtin_bit_cast(f16x8, t);
  }
  f16x8 wfi[16];
  if (l == 0) {
#pragma unroll
    for (int ks = 0; ks < 2; ks++) {
      u32x4 t = *(const u32x4*)(wih_l + (size_t)grow * NIN + ks * 32 + quad * 8);
      asm volatile("" : "+v"(t));
      wfi[ks] = __builtin_bit_cast(f16x8, t);
    }
  } else {
#pragma unroll
    for (int ks = 0; ks < 16; ks++) {
      u32x4 t = *(const u32x4*)(wih_l + (size_t)grow * HD + ks * 32 + quad * 8);
      asm volatile("" : "+v"(t));
      wfi[ks] = __builtin_bit_cast(f16x8, t);
    }
  }

  // --- per-thread elementwise state: (b,hl) ---
  const int b_  = tid >> 5;
  const int hl_ = tid & 31;
  float cv = 0.f;
  const float bv0 = bias_l[0 * HD + gi * 32 + hl_];
  const float bv1 = bias_l[1 * HD + gi * 32 + hl_];
  const float bv2 = bias_l[2 * HD + gi * 32 + hl_];
  const float bv3 = bias_l[3 * HD + gi * 32 + hl_];

  int* fown = flags + l * 256 + bi * 16;
  int* myflag = fown + gi;
  const int* fprev = (l > 0) ? (flags + (l - 1) * 256 + bi * 16) : fown;
  const int* fnext = (l < 2) ? (flags + (l + 1) * 256 + bi * 16) : fown;

  uint64_t* lh64  = (uint64_t*)lh;    // row pitch 130 u64 (=520 f16)
  uint64_t* lhp64 = (uint64_t*)lhp;

  for (int t = 0; t < S_LEN; t++) {
    // layer-0 x-tile prefetch (static data, plain load; hides under the poll)
    uint64_t xv = 0;
    if (l == 0 && tid < 256) {
      const int xr = tid >> 4, xc = tid & 15;            // 16 rows x 16 u64 (64 f16/row)
      xv = *(const uint64_t*)(xin + ((size_t)(t * 256 + bi * 16 + xr)) * NIN + xc * 4);
    }

    // ---- wave 0 polls all three flag lines; lane role = lane>>4 ----
    if (wave == 0) {
      const int* fp = fown;
      int need = t;
      if (quad == 1 && l > 0)      { fp = fprev; need = t + 1; }
      else if (quad == 2 && l < 2) { fp = fnext; need = t + 2 - RING_D; }
      int v = __hip_atomic_load(fp + ln, __ATOMIC_RELAXED, __HIP_MEMORY_SCOPE_AGENT);
      while (!__all(v >= need)) {
        __builtin_amdgcn_s_sleep(1);
        v = __hip_atomic_load(fp + ln, __ATOMIC_RELAXED, __HIP_MEMORY_SCOPE_AGENT);
      }
    }
    __syncthreads();   // releases data loads below only after flags pass

    // ---- bulk-load own h_{t-1} (slot t%D) + prev-layer h_t (slot (t+1)%D) ----
    const uint64_t* hown = (const uint64_t*)(ring
        + ((size_t)l * RING_D + (t & (RING_D - 1))) * (BATCH * HD)
        + (size_t)(bi * 16) * HD);
    uint64_t dA[4];
#pragma unroll
    for (int j = 0; j < 4; j++)
      dA[j] = __hip_atomic_load(hown + j * 512 + tid, __ATOMIC_RELAXED, __HIP_MEMORY_SCOPE_AGENT);

    if (l > 0) {
      const uint64_t* hprev = (const uint64_t*)(ring
          + ((size_t)(l - 1) * RING_D + ((t + 1) & (RING_D - 1))) * (BATCH * HD)
          + (size_t)(bi * 16) * HD);
      uint64_t dB[4];
#pragma unroll
      for (int j = 0; j < 4; j++)
        dB[j] = __hip_atomic_load(hprev + j * 512 + tid, __ATOMIC_RELAXED, __HIP_MEMORY_SCOPE_AGENT);
#pragma unroll
      for (int j = 0; j < 4; j++) {
        const int e = j * 512 + tid, row = e >> 7, c8 = e & 127;
        lhp64[row * 130 + c8] = dB[j];
      }
    } else {
      if (tid < 256) lhp64[(tid >> 4) * 130 + (tid & 15)] = xv;
    }
#pragma unroll
    for (int j = 0; j < 4; j++) {
      const int e = j * 512 + tid, row = e >> 7, c8 = e & 127;
      lh64[row * 130 + c8] = dA[j];
    }
    __syncthreads();   // staging complete

    // ---- gates = h_{t-1} @ Whh^T  +  in_t @ Wih^T   (one fp32 acc) ----
    f32x4 acc = {0.f, 0.f, 0.f, 0.f};
#pragma unroll
    for (int ks = 0; ks < 16; ks++) {
      f16x8 af = *(const f16x8*)&lh[ln * 520 + ks * 32 + quad * 8];
      acc = __builtin_amdgcn_mfma_f32_16x16x32_f16(af, wfh[ks], acc, 0, 0, 0);
    }
    if (l == 0) {
#pragma unroll
      for (int ks = 0; ks < 2; ks++) {
        f16x8 ap = *(const f16x8*)&lhp[ln * 520 + ks * 32 + quad * 8];
        acc = __builtin_amdgcn_mfma_f32_16x16x32_f16(ap, wfi[ks], acc, 0, 0, 0);
      }
    } else {
#pragma unroll
      for (int ks = 0; ks < 16; ks++) {
        f16x8 ap = *(const f16x8*)&lhp[ln * 520 + ks * 32 + quad * 8];
        acc = __builtin_amdgcn_mfma_f32_16x16x32_f16(ap, wfi[ks], acc, 0, 0, 0);
      }
    }
    const int gcol = (wave >> 1) * 32 + (wave & 1) * 16 + ln;
#pragma unroll
    for (int rr = 0; rr < 4; rr++)
      lgate[(quad * 4 + rr) * 132 + gcol] = acc[rr];
    __syncthreads();   // gates complete

    // ---- elementwise LSTM update ----
    {
      float gi_ = lgate[b_ * 132 + 0  + hl_] + bv0;
      float gf_ = lgate[b_ * 132 + 32 + hl_] + bv1;
      float gg_ = lgate[b_ * 132 + 64 + hl_] + bv2;
      float go_ = lgate[b_ * 132 + 96 + hl_] + bv3;
      const float igt = 1.f / (1.f + expf(-gi_));
      const float fgt = 1.f / (1.f + expf(-gf_));
      const float ggt = gg_ > 0.f ? gg_ : expm1f(gg_);
      const float ogt = 1.f / (1.f + expf(-go_));
      cv = fgt * cv + igt * ggt;
      const float hv = ogt * (cv > 0.f ? cv : expm1f(cv));
      f16 hv16 = (f16)hv;
      unsigned short us;
      __builtin_memcpy(&us, &hv16, 2);
      const size_t col = (size_t)(bi * 16 + b_) * HD + gi * 32 + hl_;
      __hip_atomic_store((unsigned short*)(ring
            + ((size_t)l * RING_D + ((t + 1) & (RING_D - 1))) * (BATCH * HD) + col),
          us, __ATOMIC_RELAXED, __HIP_MEMORY_SCOPE_AGENT);
      if (l == 2 && t == S_LEN - 1)
        hlast[col] = hv16;
    }
    __syncthreads();   // drains every wave's vmcnt -> all data stores at coherence point
    if (tid == 0)
      __hip_atomic_store(myflag, t + 1, __ATOMIC_RELAXED, __HIP_MEMORY_SCOPE_AGENT);
  }
}

// ====================== final FC: y[b] = h_last[b,:] . fc_w + fc_b ======================
__global__ __launch_bounds__(64) void k_fc(const f16* __restrict__ hlast,
                                           const float* __restrict__ fcw,
                                           const float* __restrict__ fcb,
                                           float* __restrict__ out) {
  const int b = blockIdx.x, lane = threadIdx.x;
  const f16* hp = hlast + (size_t)b * HD + lane * 8;
  float s = 0.f;
#pragma unroll
  for (int j = 0; j < 8; j++) s += (float)hp[j] * fcw[lane * 8 + j];
  for (int off = 32; off; off >>= 1) s += __shfl_down(s, off);
  if (lane == 0) out[b] = s + fcb[0];
}

// ============================ host ============================
extern "C" void kernel_launch(void* const* d_in, const int* in_sizes, int n_in,
                              void* d_out, int out_size, void* d_ws, size_t ws_size,
                              hipStream_t stream) {
  (void)in_sizes; (void)n_in; (void)out_size; (void)ws_size;
  const float* x      = (const float*)d_in[0];
  const float* wih[3] = {(const float*)d_in[1], (const float*)d_in[4], (const float*)d_in[7]};
  const float* whh[3] = {(const float*)d_in[2], (const float*)d_in[5], (const float*)d_in[8]};
  const float* bia[3] = {(const float*)d_in[3], (const float*)d_in[6], (const float*)d_in[9]};
  const float* fcw = (const float*)d_in[10];
  const float* fcb = (const float*)d_in[11];
  float* out = (float*)d_out;

  char* ws = (char*)d_ws;
  size_t off = 0;
  auto alloc = [&](size_t bytes) -> char* {
    off = (off + 255) & ~(size_t)255;
    char* p = ws + off;
    off += bytes;
    return p;
  };

  f16* xin   = (f16*)alloc((size_t)S_LEN * BATCH * NIN * 2);          // 16 MB
  f16* wih16 = (f16*)alloc((size_t)3 * G4 * HD * 2);                  // 12 MB (layer0 slot part-used)
  f16* whh16 = (f16*)alloc((size_t)3 * G4 * HD * 2);                  // 12 MB
  f16* ring  = (f16*)alloc((size_t)3 * RING_D * BATCH * HD * 2);      // 25 MB
  int* flags = (int*)alloc(3 * 256 * 4);
  f16* hlast = (f16*)alloc((size_t)BATCH * HD * 2);

  // ---- prep ----
  {
    int n = S_LEN * BATCH * NIN;
    k_x_transpose<<<dim3(n / 256), dim3(256), 0, stream>>>(x, xin);
  }
  k_f32_to_f16<<<dim3((G4 * NIN + 255) / 256), dim3(256), 0, stream>>>(wih[0], wih16, G4 * NIN);
  k_f32_to_f16<<<dim3((G4 * HD + 255) / 256), dim3(256), 0, stream>>>(wih[1], wih16 + (size_t)G4 * HD, G4 * HD);
  k_f32_to_f16<<<dim3((G4 * HD + 255) / 256), dim3(256), 0, stream>>>(wih[2], wih16 + (size_t)2 * G4 * HD, G4 * HD);
  for (int l = 0; l < 3; l++)
    k_f32_to_f16<<<dim3((G4 * HD + 255) / 256), dim3(256), 0, stream>>>(whh[l], whh16 + (size_t)l * G4 * HD, G4 * HD);
  // zero ring slot 0 of each layer (h_{-1}=0) + flags
  for (int l = 0; l < 3; l++)
    k_zero_i32<<<dim3(BATCH * HD / 2 / 256), dim3(256), 0, stream>>>(
        (uint32_t*)(ring + (size_t)l * RING_D * BATCH * HD), BATCH * HD / 2);
  k_zero_i32<<<dim3(3), dim3(256), 0, stream>>>((uint32_t*)flags, 3 * 256);

  // ---- single fused systolic launch: all 3 layers pipelined ----
  k_fused<<<dim3(768), dim3(512), 0, stream>>>(whh16, wih16, bia[0], bia[1], bia[2],
                                               xin, ring, flags, hlast);

  // ---- final FC ----
  k_fc<<<dim3(BATCH), dim3(64), 0, stream>>>(hlast, fcw, fcb, out);
}

// Round 2
// 5835.656 us; speedup vs baseline: 1.8722x; 1.8722x over previous
//
#include <hip/hip_runtime.h>
#include <stdint.h>
#include <stddef.h>

#define S_LEN 512
#define BATCH 256
#define NIN   64
#define HD    512
#define G4    2048   // 4*H
#define RING_D 32    // ring depth (pow2); back-pressure slack = 30 steps
#define BT    64     // batch rows per WG (4 bi tiles)

typedef _Float16 f16;
typedef _Float16 f16x8 __attribute__((ext_vector_type(8)));
typedef float    f32x4 __attribute__((ext_vector_type(4)));
typedef uint32_t u32x4 __attribute__((ext_vector_type(4)));

// ============================ prep kernels ============================
__global__ void k_f32_to_f16(const float* __restrict__ src, f16* __restrict__ dst, int n) {
  int i = blockIdx.x * 256 + threadIdx.x;
  if (i < n) dst[i] = (f16)src[i];
}

// x [B,S,I] fp32 -> xin [(s*256+b)*64+i] fp16
__global__ void k_x_transpose(const float* __restrict__ x, f16* __restrict__ xin) {
  int idx = blockIdx.x * 256 + threadIdx.x;
  int i  = idx & 63;
  int sb = idx >> 6;
  int b  = sb & 255;
  int s  = sb >> 8;
  xin[idx] = (f16)x[((size_t)b * S_LEN + s) * NIN + i];
}

__global__ void k_zero_i32(uint32_t* p, int n) {
  int i = blockIdx.x * 256 + threadIdx.x;
  if (i < n) p[i] = 0u;
}

// ====================== fused 3-layer systolic LSTM (fat-WG retile) ======================
// 192 WGs x 512 threads. blockIdx = l*64 + bi*16 + gi. WG (l,bi,gi): layer l, batch rows
// [bi*64,+64), hidden cols [gi*32,+32) x 4 gates (128 gate-cols). LDS 128 KiB -> exactly
// 1 WG/CU -> all 192 resident (<=256 CUs), 2 waves/SIMD -> VGPR cap 256: the 128 VGPRs of
// weight fragments (Whh + Wih, 16 gate-cols x K=512 each per wave) stay REGISTER-RESIDENT
// (R1 failure: launch_bounds(512,6) capped VGPR at ~85 -> weights in scratch -> 201MB/step
// scratch storm, 30GB FETCH, 21us/step).
//
// Per step t, WG of layer l:
//   own-layer flags >= t        (h_{l,t-1} in ring slot t%D)
//   prev-layer flags >= t+1     (h_{l-1,t} in slot (t+1)%D)   [l>0; l==0 reads static x]
//   next-layer flags >= t+2-D   (back-pressure before overwriting slot (t+1)%D)
// Wave 0 polls the 3 flag lines (quad roles); data ring is plain f16 read ONCE per step
// via relaxed agent u64 loads (MALL path). Producer bumps flag only after a __syncthreads
// that drains its data-store vmcnt (R6-proven protocol).
//
// LDS (131072 B): lh [64 rows][1024 B] (own h_{t-1}), lhp [64][1024] (prev h_t / x tile).
// XOR swizzle byte ^= (row&7)<<4 on BOTH write and read (kills the pitch-520 8-way
// conflicts of R0/R1). lgate (64x128 f32, 32 KiB) ALIASES lh - separated by a barrier
// after all MFMA reads complete.
__global__ __launch_bounds__(512, 2) void k_fused(
    const f16* __restrict__ whh,     // [3][2048][512] fp16
    const f16* __restrict__ wih,     // [3][2048][512] fp16 (layer0 slab uses [2048][64])
    const float* __restrict__ b0,
    const float* __restrict__ b1,
    const float* __restrict__ b2,
    const f16* __restrict__ xin,     // [512*256][64] fp16
    f16* __restrict__ ring,          // [3][RING_D][256][512] fp16
    int* __restrict__ flags,         // [3][4][16]
    f16* __restrict__ hlast) {       // [256][512] fp16
  const int tid  = threadIdx.x;
  const int lane = tid & 63;
  const int wave = tid >> 6;          // 0..7
  const int bidx = blockIdx.x;
  const int l    = bidx >> 6;         // 0..2
  const int bi   = (bidx >> 4) & 3;   // 0..3
  const int gi   = bidx & 15;         // 0..15
  const int ln   = lane & 15;
  const int quad = lane >> 4;

  __shared__ __align__(16) char smem[131072];
  char* lh_b  = smem;                 // 64 KiB: own h tile
  char* lhp_b = smem + 65536;         // 64 KiB: prev h tile / x tile
  float* lgate = (float*)smem;        // 32 KiB, aliases lh (barrier-separated)

  // byte offset with XOR swizzle (write and read sides identical)
  auto swz = [](int row, int boff) { return row * 1024 + (boff ^ ((row & 7) << 4)); };

  const f16* whh_l = whh + (size_t)l * G4 * HD;
  const f16* wih_l = wih + (size_t)l * G4 * HD;
  const float* bias_l = (l == 0) ? b0 : (l == 1 ? b1 : b2);

  // --- weight fragments -> registers (once); asm launder pins them ---
  const int grow = (wave >> 1) * HD + gi * 32 + (wave & 1) * 16 + ln; // row in [2048,K]
  f16x8 wfh[16];
#pragma unroll
  for (int ks = 0; ks < 16; ks++) {
    u32x4 t = *(const u32x4*)(whh_l + (size_t)grow * HD + ks * 32 + quad * 8);
    asm volatile("" : "+v"(t));
    wfh[ks] = __builtin_bit_cast(f16x8, t);
  }
  f16x8 wfi[16];
  if (l == 0) {
#pragma unroll
    for (int ks = 0; ks < 2; ks++) {
      u32x4 t = *(const u32x4*)(wih_l + (size_t)grow * NIN + ks * 32 + quad * 8);
      asm volatile("" : "+v"(t));
      wfi[ks] = __builtin_bit_cast(f16x8, t);
    }
  } else {
#pragma unroll
    for (int ks = 0; ks < 16; ks++) {
      u32x4 t = *(const u32x4*)(wih_l + (size_t)grow * HD + ks * 32 + quad * 8);
      asm volatile("" : "+v"(t));
      wfi[ks] = __builtin_bit_cast(f16x8, t);
    }
  }

  // --- per-thread elementwise state: 4 rows x 1 col each ---
  const int brow = tid >> 5;          // 0..15 (rows brow, brow+16, brow+32, brow+48)
  const int hl_  = tid & 31;
  float cv[4] = {0.f, 0.f, 0.f, 0.f};
  const float bv0 = bias_l[0 * HD + gi * 32 + hl_];
  const float bv1 = bias_l[1 * HD + gi * 32 + hl_];
  const float bv2 = bias_l[2 * HD + gi * 32 + hl_];
  const float bv3 = bias_l[3 * HD + gi * 32 + hl_];

  int* fown = flags + l * 64 + bi * 16;
  int* myflag = fown + gi;
  const int* fprev = (l > 0) ? (flags + (l - 1) * 64 + bi * 16) : fown;
  const int* fnext = (l < 2) ? (flags + (l + 1) * 64 + bi * 16) : fown;

  for (int t = 0; t < S_LEN; t++) {
    // layer-0 x-tile prefetch (static data; hides under the poll)
    u32x4 xv = {};
    if (l == 0) {
      const int xr = tid >> 3, xc = tid & 7;   // 64 rows x 8 chunks of 16B
      xv = *(const u32x4*)(xin + ((size_t)(t * 256 + bi * BT + xr)) * NIN + xc * 8);
    }

    // ---- wave 0 polls the three flag lines ----
    if (wave == 0) {
      const int* fp = fown;
      int need = t;
      if (quad == 1 && l > 0)      { fp = fprev; need = t + 1; }
      else if (quad == 2 && l < 2) { fp = fnext; need = t + 2 - RING_D; }
      int v = __hip_atomic_load(fp + ln, __ATOMIC_RELAXED, __HIP_MEMORY_SCOPE_AGENT);
      while (!__all(v >= need)) {
        __builtin_amdgcn_s_sleep(1);
        v = __hip_atomic_load(fp + ln, __ATOMIC_RELAXED, __HIP_MEMORY_SCOPE_AGENT);
      }
    }
    __syncthreads();   // BAR A: flags passed; also protects lh/lgate reuse from step t-1

    // ---- stage own h_{t-1} (64 rows x 512) + prev h_t -> LDS, swizzled ----
    const uint64_t* hown = (const uint64_t*)(ring
        + ((size_t)l * RING_D + (t & (RING_D - 1))) * (BATCH * HD)
        + (size_t)(bi * BT) * HD);
    uint64_t dA[16];
#pragma unroll
    for (int j = 0; j < 16; j++)
      dA[j] = __hip_atomic_load(hown + j * 512 + tid, __ATOMIC_RELAXED, __HIP_MEMORY_SCOPE_AGENT);

    if (l > 0) {
      const uint64_t* hprev = (const uint64_t*)(ring
          + ((size_t)(l - 1) * RING_D + ((t + 1) & (RING_D - 1))) * (BATCH * HD)
          + (size_t)(bi * BT) * HD);
      uint64_t dB[16];
#pragma unroll
      for (int j = 0; j < 16; j++)
        dB[j] = __hip_atomic_load(hprev + j * 512 + tid, __ATOMIC_RELAXED, __HIP_MEMORY_SCOPE_AGENT);
#pragma unroll
      for (int j = 0; j < 16; j++) {
        const int e = j * 512 + tid, row = e >> 7, c8 = e & 127;
        *(uint64_t*)(lhp_b + swz(row, c8 * 8)) = dB[j];
      }
    } else {
      const int xr = tid >> 3, xc = tid & 7;
      *(u32x4*)(lhp_b + swz(xr, xc * 16)) = xv;
    }
#pragma unroll
    for (int j = 0; j < 16; j++) {
      const int e = j * 512 + tid, row = e >> 7, c8 = e & 127;
      *(uint64_t*)(lh_b + swz(row, c8 * 8)) = dA[j];
    }
    __syncthreads();   // BAR B: staging complete

    // ---- gates = h_{t-1} @ Whh^T + in_t @ Wih^T  (M=64: 4 M-tiles per wave) ----
    f32x4 acc[4] = {};
#pragma unroll
    for (int ks = 0; ks < 16; ks++) {
#pragma unroll
      for (int mi = 0; mi < 4; mi++) {
        const f16x8 af = *(const f16x8*)(lh_b + swz(mi * 16 + ln, ks * 64 + quad * 16));
        acc[mi] = __builtin_amdgcn_mfma_f32_16x16x32_f16(af, wfh[ks], acc[mi], 0, 0, 0);
      }
    }
    if (l == 0) {
#pragma unroll
      for (int ks = 0; ks < 2; ks++) {
#pragma unroll
        for (int mi = 0; mi < 4; mi++) {
          const f16x8 ap = *(const f16x8*)(lhp_b + swz(mi * 16 + ln, ks * 64 + quad * 16));
          acc[mi] = __builtin_amdgcn_mfma_f32_16x16x32_f16(ap, wfi[ks], acc[mi], 0, 0, 0);
        }
      }
    } else {
#pragma unroll
      for (int ks = 0; ks < 16; ks++) {
#pragma unroll
        for (int mi = 0; mi < 4; mi++) {
          const f16x8 ap = *(const f16x8*)(lhp_b + swz(mi * 16 + ln, ks * 64 + quad * 16));
          acc[mi] = __builtin_amdgcn_mfma_f32_16x16x32_f16(ap, wfi[ks], acc[mi], 0, 0, 0);
        }
      }
    }
    __syncthreads();   // BAR C: all lh/lhp reads done -> lgate may overwrite lh

    const int gcol = (wave >> 1) * 32 + (wave & 1) * 16 + ln;
#pragma unroll
    for (int mi = 0; mi < 4; mi++)
#pragma unroll
      for (int rr = 0; rr < 4; rr++)
        lgate[(mi * 16 + quad * 4 + rr) * 128 + gcol] = acc[mi][rr];
    __syncthreads();   // BAR D: gates visible

    // ---- elementwise LSTM update: 4 (row,col) states per thread ----
    f16* hout = ring + ((size_t)l * RING_D + ((t + 1) & (RING_D - 1))) * (BATCH * HD);
#pragma unroll
    for (int s = 0; s < 4; s++) {
      const int row = brow + s * 16;   // 0..63
      float g0 = lgate[row * 128 + 0  + hl_] + bv0;
      float g1 = lgate[row * 128 + 32 + hl_] + bv1;
      float g2 = lgate[row * 128 + 64 + hl_] + bv2;
      float g3 = lgate[row * 128 + 96 + hl_] + bv3;
      const float igt = 1.f / (1.f + expf(-g0));
      const float fgt = 1.f / (1.f + expf(-g1));
      const float ggt = g2 > 0.f ? g2 : expm1f(g2);
      const float ogt = 1.f / (1.f + expf(-g3));
      cv[s] = fgt * cv[s] + igt * ggt;
      const float hv = ogt * (cv[s] > 0.f ? cv[s] : expm1f(cv[s]));
      f16 hv16 = (f16)hv;
      unsigned short us;
      __builtin_memcpy(&us, &hv16, 2);
      const size_t col = (size_t)(bi * BT + row) * HD + gi * 32 + hl_;
      __hip_atomic_store((unsigned short*)(hout + col), us,
                         __ATOMIC_RELAXED, __HIP_MEMORY_SCOPE_AGENT);
      if (l == 2 && t == S_LEN - 1) hlast[col] = hv16;
    }
    __syncthreads();   // BAR E: drains vmcnt -> all h stores at the coherence point
    if (tid == 0)
      __hip_atomic_store(myflag, t + 1, __ATOMIC_RELAXED, __HIP_MEMORY_SCOPE_AGENT);
  }
}

// ====================== final FC: y[b] = h_last[b,:] . fc_w + fc_b ======================
__global__ __launch_bounds__(64) void k_fc(const f16* __restrict__ hlast,
                                           const float* __restrict__ fcw,
                                           const float* __restrict__ fcb,
                                           float* __restrict__ out) {
  const int b = blockIdx.x, lane = threadIdx.x;
  const f16* hp = hlast + (size_t)b * HD + lane * 8;
  float s = 0.f;
#pragma unroll
  for (int j = 0; j < 8; j++) s += (float)hp[j] * fcw[lane * 8 + j];
  for (int off = 32; off; off >>= 1) s += __shfl_down(s, off);
  if (lane == 0) out[b] = s + fcb[0];
}

// ============================ host ============================
extern "C" void kernel_launch(void* const* d_in, const int* in_sizes, int n_in,
                              void* d_out, int out_size, void* d_ws, size_t ws_size,
                              hipStream_t stream) {
  (void)in_sizes; (void)n_in; (void)out_size; (void)ws_size;
  const float* x      = (const float*)d_in[0];
  const float* wih[3] = {(const float*)d_in[1], (const float*)d_in[4], (const float*)d_in[7]};
  const float* whh[3] = {(const float*)d_in[2], (const float*)d_in[5], (const float*)d_in[8]};
  const float* bia[3] = {(const float*)d_in[3], (const float*)d_in[6], (const float*)d_in[9]};
  const float* fcw = (const float*)d_in[10];
  const float* fcb = (const float*)d_in[11];
  float* out = (float*)d_out;

  char* ws = (char*)d_ws;
  size_t off = 0;
  auto alloc = [&](size_t bytes) -> char* {
    off = (off + 255) & ~(size_t)255;
    char* p = ws + off;
    off += bytes;
    return p;
  };

  f16* xin   = (f16*)alloc((size_t)S_LEN * BATCH * NIN * 2);
  f16* wih16 = (f16*)alloc((size_t)3 * G4 * HD * 2);
  f16* whh16 = (f16*)alloc((size_t)3 * G4 * HD * 2);
  f16* ring  = (f16*)alloc((size_t)3 * RING_D * BATCH * HD * 2);
  int* flags = (int*)alloc(256 * 4);
  f16* hlast = (f16*)alloc((size_t)BATCH * HD * 2);

  // ---- prep ----
  {
    int n = S_LEN * BATCH * NIN;
    k_x_transpose<<<dim3(n / 256), dim3(256), 0, stream>>>(x, xin);
  }
  k_f32_to_f16<<<dim3((G4 * NIN + 255) / 256), dim3(256), 0, stream>>>(wih[0], wih16, G4 * NIN);
  k_f32_to_f16<<<dim3((G4 * HD + 255) / 256), dim3(256), 0, stream>>>(wih[1], wih16 + (size_t)G4 * HD, G4 * HD);
  k_f32_to_f16<<<dim3((G4 * HD + 255) / 256), dim3(256), 0, stream>>>(wih[2], wih16 + (size_t)2 * G4 * HD, G4 * HD);
  for (int l = 0; l < 3; l++)
    k_f32_to_f16<<<dim3((G4 * HD + 255) / 256), dim3(256), 0, stream>>>(whh[l], whh16 + (size_t)l * G4 * HD, G4 * HD);
  // zero ring slot 0 of each layer (h_{-1}=0) + flags
  for (int l = 0; l < 3; l++)
    k_zero_i32<<<dim3(BATCH * HD / 2 / 256), dim3(256), 0, stream>>>(
        (uint32_t*)(ring + (size_t)l * RING_D * BATCH * HD), BATCH * HD / 2);
  k_zero_i32<<<dim3(1), dim3(256), 0, stream>>>((uint32_t*)flags, 192);

  // ---- single fused systolic launch (192 fat WGs, 1/CU) ----
  k_fused<<<dim3(192), dim3(512), 0, stream>>>(whh16, wih16, bia[0], bia[1], bia[2],
                                               xin, ring, flags, hlast);

  // ---- final FC ----
  k_fc<<<dim3(BATCH), dim3(64), 0, stream>>>(hlast, fcw, fcb, out);
}

// Round 3
// 5787.580 us; speedup vs baseline: 1.8877x; 1.0083x over previous
//
#include <hip/hip_runtime.h>
#include <stdint.h>
#include <stddef.h>

#define S_LEN 512
#define BATCH 256
#define NIN   64
#define HD    512
#define G4    2048   // 4*H
#define RING_D 32    // ring depth (pow2); back-pressure slack = 30 steps
#define BT    64     // batch rows per WG

typedef _Float16 f16;
typedef _Float16 f16x8 __attribute__((ext_vector_type(8)));
typedef float    f32x4 __attribute__((ext_vector_type(4)));
typedef uint32_t u32x4 __attribute__((ext_vector_type(4)));
typedef uint64_t u64x2 __attribute__((ext_vector_type(2)));

// ============================ prep kernels ============================
__global__ void k_f32_to_f16(const float* __restrict__ src, f16* __restrict__ dst, int n) {
  int i = blockIdx.x * 256 + threadIdx.x;
  if (i < n) dst[i] = (f16)src[i];
}

// x [B,S,I] fp32 -> xin [(s*256+b)*64+i] fp16
__global__ void k_x_transpose(const float* __restrict__ x, f16* __restrict__ xin) {
  int idx = blockIdx.x * 256 + threadIdx.x;
  int i  = idx & 63;
  int sb = idx >> 6;
  int b  = sb & 255;
  int s  = sb >> 8;
  xin[idx] = (f16)x[((size_t)b * S_LEN + s) * NIN + i];
}

__global__ void k_zero_i32(uint32_t* p, int n) {
  int i = blockIdx.x * 256 + threadIdx.x;
  if (i < n) p[i] = 0u;
}

// ====================== fused 3-layer systolic LSTM — K-split wave roles ======================
// 192 WGs x 512 threads, 1 WG/CU (LDS 128 KiB). blockIdx = l*64 + bi*16 + gi.
// WG (l,bi,gi): layer l, batch rows [bi*64,+64), h-cols [gi*32,+32) (=128 gate-cols).
//
// R2 bottleneck: every wave read BOTH 64KB h-tiles (K=1024, N_wave=16) -> 1 MB LDS reads
// per WG-step ~ 4-5us. Fix: wave role (g, kh) with g = wave>>1 (gate), kh = wave&1:
//   kh=0: gates_part0 = own_h(t-1) @ Whh^T   (K=512, N=32, 128 VGPR weights, reads lh only)
//   kh=1: gates_part1 = prev_h(t) @ Wih^T    (K=512 or 64 for l==0, reads lhp only)
// -> frag reads halve to 512KB/WG-step; MFMA/wave unchanged (128). Partials summed in the
// elementwise phase (lgate0 + lgate1 + bias), numerically equivalent to one accumulator.
//
// Sync protocol IDENTICAL to proven R2 (per-(l,bi,gi) monotone flags; plain-f16 data ring
// read once via relaxed agent u64 loads; producer bumps flag only after __syncthreads
// drains its data-store vmcnt). Changes: every wave polls (R0-proven mode) -> BAR-A gone;
// 4 barriers/step. lgate0+lgate1 (64KB) alias lh (barrier-separated).
__global__ __launch_bounds__(512, 2) void k_fused(
    const f16* __restrict__ whh,     // [3][2048][512] fp16
    const f16* __restrict__ wih,     // [3] slabs of G4*HD; layer0 packed [2048][64]
    const float* __restrict__ b0,
    const float* __restrict__ b1,
    const float* __restrict__ b2,
    const f16* __restrict__ xin,     // [512*256][64] fp16
    f16* __restrict__ ring,          // [3][RING_D][256][512] fp16
    int* __restrict__ flags,         // [3][4][16]
    f16* __restrict__ hlast) {       // [256][512] fp16
  const int tid  = threadIdx.x;
  const int lane = tid & 63;
  const int wave = tid >> 6;          // 0..7
  const int l    = blockIdx.x >> 6;   // 0..2
  const int bi   = (blockIdx.x >> 4) & 3;
  const int gi   = blockIdx.x & 15;
  const int ln   = lane & 15;
  const int quad = lane >> 4;
  const int g    = wave >> 1;         // gate 0..3
  const int kh   = wave & 1;          // 0: recurrence (Whh/lh), 1: input proj (Wih/lhp)

  __shared__ __align__(16) char smem[131072];
  char*  lh_b  = smem;                 // 64 KiB own h_{t-1} tile (rows 64 x 1024B)
  char*  lhp_b = smem + 65536;         // 64 KiB prev h_t tile / x tile
  float* lg0   = (float*)smem;         // 32 KiB partial gates (kh=0), aliases lh
  float* lg1   = (float*)(smem + 32768); // 32 KiB partial gates (kh=1), aliases lh

  auto swz = [](int row, int boff) { return row * 1024 + (boff ^ ((row & 7) << 4)); };

  const f16* whh_l = whh + (size_t)l * G4 * HD;
  const f16* wih_l = wih + (size_t)l * G4 * HD;
  const float* bias_l = (l == 0) ? b0 : (l == 1 ? b1 : b2);

  // --- weight fragments -> registers: N=32 (2 sub-tiles) x K=512 = 32 frags = 128 VGPR ---
  f16x8 wf[16][2];
  if (kh == 0 || l > 0) {
    const f16* W = kh ? wih_l : whh_l;
#pragma unroll
    for (int nb = 0; nb < 2; nb++) {
      const int r = g * 512 + gi * 32 + nb * 16 + ln;   // row in [2048, 512]
#pragma unroll
      for (int ks = 0; ks < 16; ks++) {
        u32x4 tmp = *(const u32x4*)(W + (size_t)r * HD + ks * 32 + quad * 8);
        asm volatile("" : "+v"(tmp));
        wf[ks][nb] = __builtin_bit_cast(f16x8, tmp);
      }
    }
  } else {  // l==0, kh==1: Wih1 is [2048][64]
#pragma unroll
    for (int nb = 0; nb < 2; nb++) {
      const int r = g * 512 + gi * 32 + nb * 16 + ln;
#pragma unroll
      for (int ks = 0; ks < 2; ks++) {
        u32x4 tmp = *(const u32x4*)(wih_l + (size_t)r * NIN + ks * 32 + quad * 8);
        asm volatile("" : "+v"(tmp));
        wf[ks][nb] = __builtin_bit_cast(f16x8, tmp);
      }
    }
  }

  // --- per-thread elementwise state: 4 rows x 1 h-col ---
  const int brow = tid >> 5;          // 0..15 (rows brow + s*16)
  const int hl_  = tid & 31;
  float cv[4] = {0.f, 0.f, 0.f, 0.f};
  const float bv0 = bias_l[0 * HD + gi * 32 + hl_];
  const float bv1 = bias_l[1 * HD + gi * 32 + hl_];
  const float bv2 = bias_l[2 * HD + gi * 32 + hl_];
  const float bv3 = bias_l[3 * HD + gi * 32 + hl_];

  int* fown = flags + l * 64 + bi * 16;
  int* myflag = fown + gi;
  const int* fprev = (l > 0) ? (flags + (l - 1) * 64 + bi * 16) : fown;
  const int* fnext = (l < 2) ? (flags + (l + 1) * 64 + bi * 16) : fown;

  for (int t = 0; t < S_LEN; t++) {
    // ---- all waves poll the three flag lines (quad roles; R0-proven all-wave mode) ----
    {
      const int* fp = fown;
      int need = t;
      if (quad == 1 && l > 0)      { fp = fprev; need = t + 1; }
      else if (quad == 2 && l < 2) { fp = fnext; need = t + 2 - RING_D; }
      int v = __hip_atomic_load(fp + ln, __ATOMIC_RELAXED, __HIP_MEMORY_SCOPE_AGENT);
      while (!__all(v >= need)) {
        __builtin_amdgcn_s_sleep(1);
        v = __hip_atomic_load(fp + ln, __ATOMIC_RELAXED, __HIP_MEMORY_SCOPE_AGENT);
      }
    }
    asm volatile("" ::: "memory");   // keep data loads below the poll

    // ---- stage own h_{t-1} (slot t%D) and prev h_t (slot (t+1)%D) / x tile ----
    // paired-u64 loads -> b128 LDS writes (halves stage-write cycles vs R2's b64)
    const uint64_t* hown = (const uint64_t*)(ring
        + ((size_t)l * RING_D + (t & (RING_D - 1))) * (BATCH * HD)
        + (size_t)(bi * BT) * HD);
    uint64_t a0[8], a1[8];
#pragma unroll
    for (int j = 0; j < 8; j++) {
      a0[j] = __hip_atomic_load(hown + j * 1024 + tid * 2,     __ATOMIC_RELAXED, __HIP_MEMORY_SCOPE_AGENT);
      a1[j] = __hip_atomic_load(hown + j * 1024 + tid * 2 + 1, __ATOMIC_RELAXED, __HIP_MEMORY_SCOPE_AGENT);
    }
    if (l > 0) {
      const uint64_t* hprev = (const uint64_t*)(ring
          + ((size_t)(l - 1) * RING_D + ((t + 1) & (RING_D - 1))) * (BATCH * HD)
          + (size_t)(bi * BT) * HD);
      uint64_t p0[8], p1[8];
#pragma unroll
      for (int j = 0; j < 8; j++) {
        p0[j] = __hip_atomic_load(hprev + j * 1024 + tid * 2,     __ATOMIC_RELAXED, __HIP_MEMORY_SCOPE_AGENT);
        p1[j] = __hip_atomic_load(hprev + j * 1024 + tid * 2 + 1, __ATOMIC_RELAXED, __HIP_MEMORY_SCOPE_AGENT);
      }
#pragma unroll
      for (int j = 0; j < 8; j++) {
        const int e = j * 1024 + tid * 2, row = e >> 7, c8 = e & 127;
        u64x2 p; p[0] = p0[j]; p[1] = p1[j];
        *(u64x2*)(lhp_b + swz(row, c8 * 8)) = p;
      }
    } else {
      const int xr = tid >> 3, xc = tid & 7;   // 64 rows x 8 chunks of 16B
      u32x4 xv = *(const u32x4*)(xin + ((size_t)(t * 256 + bi * BT + xr)) * NIN + xc * 8);
      *(u32x4*)(lhp_b + swz(xr, xc * 16)) = xv;
    }
#pragma unroll
    for (int j = 0; j < 8; j++) {
      const int e = j * 1024 + tid * 2, row = e >> 7, c8 = e & 127;
      u64x2 p; p[0] = a0[j]; p[1] = a1[j];
      *(u64x2*)(lh_b + swz(row, c8 * 8)) = p;
    }
    __syncthreads();   // BAR1: staging complete

    // ---- partial gates: kh=0 -> lh @ Whh^T ; kh=1 -> lhp @ Wih^T  (M=64, N=32) ----
    f32x4 acc[4][2] = {};
    const char* tb = kh ? lhp_b : lh_b;
    if (kh == 0 || l > 0) {
#pragma unroll
      for (int ks = 0; ks < 16; ks++) {
        f16x8 af[4];
#pragma unroll
        for (int mi = 0; mi < 4; mi++)
          af[mi] = *(const f16x8*)(tb + swz(mi * 16 + ln, ks * 64 + quad * 16));
#pragma unroll
        for (int mi = 0; mi < 4; mi++)
#pragma unroll
          for (int nb = 0; nb < 2; nb++)
            acc[mi][nb] = __builtin_amdgcn_mfma_f32_16x16x32_f16(af[mi], wf[ks][nb], acc[mi][nb], 0, 0, 0);
      }
    } else {  // l==0 proj: K=64
#pragma unroll
      for (int ks = 0; ks < 2; ks++) {
        f16x8 af[4];
#pragma unroll
        for (int mi = 0; mi < 4; mi++)
          af[mi] = *(const f16x8*)(tb + swz(mi * 16 + ln, ks * 64 + quad * 16));
#pragma unroll
        for (int mi = 0; mi < 4; mi++)
#pragma unroll
          for (int nb = 0; nb < 2; nb++)
            acc[mi][nb] = __builtin_amdgcn_mfma_f32_16x16x32_f16(af[mi], wf[ks][nb], acc[mi][nb], 0, 0, 0);
      }
    }
    __syncthreads();   // BAR2: all frag reads done -> lgate may overwrite lh

    // ---- write partials (quad-XOR on column kills the 4-way write conflict) ----
    {
      float* lg = kh ? lg1 : lg0;
#pragma unroll
      for (int mi = 0; mi < 4; mi++)
#pragma unroll
        for (int nb = 0; nb < 2; nb++)
#pragma unroll
          for (int rr = 0; rr < 4; rr++) {
            const int row = mi * 16 + quad * 4 + rr;
            const int col = g * 32 + nb * 16 + ln;
            lg[row * 128 + (col ^ (((row >> 2) & 7) << 2))] = acc[mi][nb][rr];
          }
    }
    __syncthreads();   // BAR3: partials visible

    // ---- elementwise LSTM update: 4 (row, h-col) states per thread ----
    f16* hout = ring + ((size_t)l * RING_D + ((t + 1) & (RING_D - 1))) * (BATCH * HD);
#pragma unroll
    for (int s = 0; s < 4; s++) {
      const int row = brow + s * 16;   // 0..63
      const int xm = ((row >> 2) & 7) << 2;
      const int rb = row * 128;
      float g0 = lg0[rb + ((0  + hl_) ^ xm)] + lg1[rb + ((0  + hl_) ^ xm)] + bv0;
      float g1 = lg0[rb + ((32 + hl_) ^ xm)] + lg1[rb + ((32 + hl_) ^ xm)] + bv1;
      float g2 = lg0[rb + ((64 + hl_) ^ xm)] + lg1[rb + ((64 + hl_) ^ xm)] + bv2;
      float g3 = lg0[rb + ((96 + hl_) ^ xm)] + lg1[rb + ((96 + hl_) ^ xm)] + bv3;
      const float igt = 1.f / (1.f + __expf(-g0));
      const float fgt = 1.f / (1.f + __expf(-g1));
      const float ggt = g2 > 0.f ? g2 : expm1f(g2);
      const float ogt = 1.f / (1.f + __expf(-g3));
      cv[s] = fgt * cv[s] + igt * ggt;
      const float hv = ogt * (cv[s] > 0.f ? cv[s] : expm1f(cv[s]));
      f16 hv16 = (f16)hv;
      unsigned short us;
      __builtin_memcpy(&us, &hv16, 2);
      const size_t col = (size_t)(bi * BT + row) * HD + gi * 32 + hl_;
      __hip_atomic_store((unsigned short*)(hout + col), us,
                         __ATOMIC_RELAXED, __HIP_MEMORY_SCOPE_AGENT);
      if (l == 2 && t == S_LEN - 1) hlast[col] = hv16;
    }
    __syncthreads();   // BAR4: drains vmcnt -> all h stores at the coherence point
    if (tid == 0)
      __hip_atomic_store(myflag, t + 1, __ATOMIC_RELAXED, __HIP_MEMORY_SCOPE_AGENT);
  }
}

// ====================== final FC: y[b] = h_last[b,:] . fc_w + fc_b ======================
__global__ __launch_bounds__(64) void k_fc(const f16* __restrict__ hlast,
                                           const float* __restrict__ fcw,
                                           const float* __restrict__ fcb,
                                           float* __restrict__ out) {
  const int b = blockIdx.x, lane = threadIdx.x;
  const f16* hp = hlast + (size_t)b * HD + lane * 8;
  float s = 0.f;
#pragma unroll
  for (int j = 0; j < 8; j++) s += (float)hp[j] * fcw[lane * 8 + j];
  for (int off = 32; off; off >>= 1) s += __shfl_down(s, off);
  if (lane == 0) out[b] = s + fcb[0];
}

// ============================ host ============================
extern "C" void kernel_launch(void* const* d_in, const int* in_sizes, int n_in,
                              void* d_out, int out_size, void* d_ws, size_t ws_size,
                              hipStream_t stream) {
  (void)in_sizes; (void)n_in; (void)out_size; (void)ws_size;
  const float* x      = (const float*)d_in[0];
  const float* wih[3] = {(const float*)d_in[1], (const float*)d_in[4], (const float*)d_in[7]};
  const float* whh[3] = {(const float*)d_in[2], (const float*)d_in[5], (const float*)d_in[8]};
  const float* bia[3] = {(const float*)d_in[3], (const float*)d_in[6], (const float*)d_in[9]};
  const float* fcw = (const float*)d_in[10];
  const float* fcb = (const float*)d_in[11];
  float* out = (float*)d_out;

  char* ws = (char*)d_ws;
  size_t off = 0;
  auto alloc = [&](size_t bytes) -> char* {
    off = (off + 255) & ~(size_t)255;
    char* p = ws + off;
    off += bytes;
    return p;
  };

  f16* xin   = (f16*)alloc((size_t)S_LEN * BATCH * NIN * 2);
  f16* wih16 = (f16*)alloc((size_t)3 * G4 * HD * 2);
  f16* whh16 = (f16*)alloc((size_t)3 * G4 * HD * 2);
  f16* ring  = (f16*)alloc((size_t)3 * RING_D * BATCH * HD * 2);
  int* flags = (int*)alloc(256 * 4);
  f16* hlast = (f16*)alloc((size_t)BATCH * HD * 2);

  // ---- prep ----
  {
    int n = S_LEN * BATCH * NIN;
    k_x_transpose<<<dim3(n / 256), dim3(256), 0, stream>>>(x, xin);
  }
  k_f32_to_f16<<<dim3((G4 * NIN + 255) / 256), dim3(256), 0, stream>>>(wih[0], wih16, G4 * NIN);
  k_f32_to_f16<<<dim3((G4 * HD + 255) / 256), dim3(256), 0, stream>>>(wih[1], wih16 + (size_t)G4 * HD, G4 * HD);
  k_f32_to_f16<<<dim3((G4 * HD + 255) / 256), dim3(256), 0, stream>>>(wih[2], wih16 + (size_t)2 * G4 * HD, G4 * HD);
  for (int l = 0; l < 3; l++)
    k_f32_to_f16<<<dim3((G4 * HD + 255) / 256), dim3(256), 0, stream>>>(whh[l], whh16 + (size_t)l * G4 * HD, G4 * HD);
  // zero ring slot 0 of each layer (h_{-1}=0) + flags
  for (int l = 0; l < 3; l++)
    k_zero_i32<<<dim3(BATCH * HD / 2 / 256), dim3(256), 0, stream>>>(
        (uint32_t*)(ring + (size_t)l * RING_D * BATCH * HD), BATCH * HD / 2);
  k_zero_i32<<<dim3(1), dim3(256), 0, stream>>>((uint32_t*)flags, 192);

  // ---- single fused systolic launch (192 WGs, 1/CU, K-split wave roles) ----
  k_fused<<<dim3(192), dim3(512), 0, stream>>>(whh16, wih16, bia[0], bia[1], bia[2],
                                               xin, ring, flags, hlast);

  // ---- final FC ----
  k_fc<<<dim3(BATCH), dim3(64), 0, stream>>>(hlast, fcw, fcb, out);
}